// Round 1
// baseline (1168.285 us; speedup 1.0000x reference)
//
#include <hip/hip_runtime.h>
#include <math.h>

#define NN 50000
#define NE 1600000
#define DF 256

#define BM 128
#define BN 128
#define BK 16
#define LSTR 132   // padded LDS leading stride (floats); 132*4 % 16 == 0 (float4-aligned), breaks pow2 bank patterns

// ---------------- CSR build ----------------

__global__ void k_zero(int* __restrict__ deg, int* __restrict__ cursor, float* __restrict__ nrm) {
    int i = blockIdx.x * 256 + threadIdx.x;
    if (i < NN) { deg[i] = 0; cursor[i] = 0; }
    if (i == 0) *nrm = 0.0f;
}

__global__ void k_hist(const int* __restrict__ dst, int* __restrict__ deg) {
    int e = blockIdx.x * 256 + threadIdx.x;
    if (e < NE) atomicAdd(&deg[dst[e]], 1);
}

__global__ void k_scan1(const int* __restrict__ deg, int* __restrict__ row_ptr, int* __restrict__ bsums) {
    __shared__ int s[256];
    int t = threadIdx.x, i = blockIdx.x * 256 + t;
    int v = (i < NN) ? deg[i] : 0;
    s[t] = v; __syncthreads();
    for (int off = 1; off < 256; off <<= 1) {
        int x = (t >= off) ? s[t - off] : 0;
        __syncthreads();
        s[t] += x;
        __syncthreads();
    }
    if (i < NN) row_ptr[i] = s[t] - v;   // exclusive
    if (t == 255) bsums[blockIdx.x] = s[255];
}

__global__ void k_scan2(const int* __restrict__ bsums, int* __restrict__ boffs, int nb) {
    __shared__ int s[256];
    int t = threadIdx.x;
    int v = (t < nb) ? bsums[t] : 0;
    s[t] = v; __syncthreads();
    for (int off = 1; off < 256; off <<= 1) {
        int x = (t >= off) ? s[t - off] : 0;
        __syncthreads();
        s[t] += x;
        __syncthreads();
    }
    if (t < nb) boffs[t] = s[t] - v;     // exclusive
}

__global__ void k_addoff(int* __restrict__ row_ptr, const int* __restrict__ boffs) {
    int i = blockIdx.x * 256 + threadIdx.x;
    if (i < NN) row_ptr[i] += boffs[blockIdx.x];
    if (i == 0) row_ptr[NN] = NE;
}

__global__ void k_fill(const int* __restrict__ src, const int* __restrict__ dst,
                       const int* __restrict__ row_ptr, int* __restrict__ cursor,
                       int* __restrict__ csr_src) {
    int e = blockIdx.x * 256 + threadIdx.x;
    if (e < NE) {
        int d = dst[e];
        int pos = row_ptr[d] + atomicAdd(&cursor[d], 1);
        csr_src[pos] = src[e];
    }
}

// ---------------- neighbor mean aggregation ----------------
// one wave per dst node; lane holds a float4 column slice (64*4 = 256 feats)

__global__ __launch_bounds__(256)
void k_agg(const float* __restrict__ feat, const int* __restrict__ gather,
           const int* __restrict__ row_ptr, const int* __restrict__ csr_src,
           float* __restrict__ out) {
    int node = blockIdx.x * 4 + (threadIdx.x >> 6);
    int lane = threadIdx.x & 63;
    if (node >= NN) return;
    int beg = row_ptr[node], end = row_ptr[node + 1];
    float ax = 0.f, ay = 0.f, az = 0.f, aw = 0.f;
    for (int p = beg; p < end; ++p) {
        int s = csr_src[p];
        if (gather) s = gather[s];
        const float4 v = *(const float4*)(feat + (long long)s * DF + lane * 4);
        ax += v.x; ay += v.y; az += v.z; aw += v.w;
    }
    float inv = 1.0f / fmaxf((float)(end - beg), 1.0f);
    float4 r; r.x = ax * inv; r.y = ay * inv; r.z = az * inv; r.w = aw * inv;
    *(float4*)(out + (long long)node * DF + lane * 4) = r;
}

// ---------------- fused dual GEMM ----------------
// C[N,256] = Aself@Wself + Aneigh@Wneigh + bias  (+relu / +global sumsq)
// viewed as K=512 concat GEMM; 128x128 block tile, 8x8 per thread fp32.

template<int RELU, int NORM>
__global__ __launch_bounds__(256, 2)
void k_gemm(const float* __restrict__ Aself, const int* __restrict__ gather,
            const float* __restrict__ Aneigh,
            const float* __restrict__ Wself, const float* __restrict__ Wneigh,
            const float* __restrict__ bias,
            float* __restrict__ C, float* __restrict__ norm_acc) {
    __shared__ float As[BK * LSTR];   // transposed: [k][m]
    __shared__ float Wt[BK * LSTR];   // natural:    [k][n]
    __shared__ float red[4];

    const int t  = threadIdx.x;
    const int m0 = blockIdx.x * BM;
    const int n0 = blockIdx.y * BN;
    const int tx = t & 15;     // n-dim
    const int ty = t >> 4;     // m-dim

    // A staging: thread loads rows ar, ar+64 at k-cols ac..ac+3
    const int ar = t >> 2;
    const int ac = (t & 3) * 4;
    // W staging: thread loads k-rows wk, wk+8 at n-cols wc..wc+3
    const int wk = t >> 5;
    const int wc = (t & 31) * 4;

    float acc[8][8];
#pragma unroll
    for (int i = 0; i < 8; ++i)
#pragma unroll
        for (int j = 0; j < 8; ++j) acc[i][j] = 0.0f;

    const int mA0 = min(m0 + ar, NN - 1);
    const int mA1 = min(m0 + ar + 64, NN - 1);
    const long long rs0 = (long long)(gather ? gather[mA0] : mA0) * DF;
    const long long rs1 = (long long)(gather ? gather[mA1] : mA1) * DF;
    const long long rn0 = (long long)mA0 * DF;
    const long long rn1 = (long long)mA1 * DF;

    for (int kt = 0; kt < 2 * DF; kt += BK) {
        const bool self = kt < DF;
        const int  kk   = self ? kt : kt - DF;
        const float* Ab = self ? Aself : Aneigh;
        const long long r0 = self ? rs0 : rn0;
        const long long r1 = self ? rs1 : rn1;
        const float* Wb = self ? Wself : Wneigh;

        const float4 a0 = *(const float4*)(Ab + r0 + kk + ac);
        const float4 a1 = *(const float4*)(Ab + r1 + kk + ac);
        const float4 w0 = *(const float4*)(Wb + (long long)(kk + wk) * DF + n0 + wc);
        const float4 w1 = *(const float4*)(Wb + (long long)(kk + wk + 8) * DF + n0 + wc);

        __syncthreads();
        As[(ac + 0) * LSTR + ar] = a0.x;
        As[(ac + 1) * LSTR + ar] = a0.y;
        As[(ac + 2) * LSTR + ar] = a0.z;
        As[(ac + 3) * LSTR + ar] = a0.w;
        As[(ac + 0) * LSTR + ar + 64] = a1.x;
        As[(ac + 1) * LSTR + ar + 64] = a1.y;
        As[(ac + 2) * LSTR + ar + 64] = a1.z;
        As[(ac + 3) * LSTR + ar + 64] = a1.w;
        *(float4*)&Wt[wk * LSTR + wc] = w0;
        *(float4*)&Wt[(wk + 8) * LSTR + wc] = w1;
        __syncthreads();

#pragma unroll
        for (int k = 0; k < BK; ++k) {
            const float4 av0 = *(const float4*)&As[k * LSTR + ty * 4];
            const float4 av1 = *(const float4*)&As[k * LSTR + 64 + ty * 4];
            const float4 wv0 = *(const float4*)&Wt[k * LSTR + tx * 4];
            const float4 wv1 = *(const float4*)&Wt[k * LSTR + 64 + tx * 4];
            const float a[8] = {av0.x, av0.y, av0.z, av0.w, av1.x, av1.y, av1.z, av1.w};
            const float w[8] = {wv0.x, wv0.y, wv0.z, wv0.w, wv1.x, wv1.y, wv1.z, wv1.w};
#pragma unroll
            for (int i = 0; i < 8; ++i)
#pragma unroll
                for (int j = 0; j < 8; ++j)
                    acc[i][j] = fmaf(a[i], w[j], acc[i][j]);
        }
    }

    // epilogue
    float sumsq = 0.0f;
#pragma unroll
    for (int i = 0; i < 8; ++i) {
        const int mrow = (i < 4) ? (ty * 4 + i) : (64 + ty * 4 + i - 4);
        const int m = m0 + mrow;
        if (m < NN) {
#pragma unroll
            for (int jh = 0; jh < 2; ++jh) {
                const int nb = n0 + jh * 64 + tx * 4;
                float4 v;
                v.x = acc[i][jh * 4 + 0] + bias[nb + 0];
                v.y = acc[i][jh * 4 + 1] + bias[nb + 1];
                v.z = acc[i][jh * 4 + 2] + bias[nb + 2];
                v.w = acc[i][jh * 4 + 3] + bias[nb + 3];
                if (RELU) {
                    v.x = fmaxf(v.x, 0.f); v.y = fmaxf(v.y, 0.f);
                    v.z = fmaxf(v.z, 0.f); v.w = fmaxf(v.w, 0.f);
                }
                *(float4*)&C[(long long)m * DF + nb] = v;
                if (NORM) sumsq += v.x * v.x + v.y * v.y + v.z * v.z + v.w * v.w;
            }
        }
    }

    if (NORM) {
#pragma unroll
        for (int off = 32; off > 0; off >>= 1) sumsq += __shfl_down(sumsq, off);
        if ((t & 63) == 0) red[t >> 6] = sumsq;
        __syncthreads();
        if (t == 0) atomicAdd(norm_acc, red[0] + red[1] + red[2] + red[3]);
    }
}

__global__ void k_scale(float* __restrict__ out, const float* __restrict__ nrm) {
    const float s = 1.0f / sqrtf(*nrm);
    long long i = (long long)(blockIdx.x * 256 + threadIdx.x) * 4;
    float4 v = *(float4*)&out[i];
    v.x *= s; v.y *= s; v.z *= s; v.w *= s;
    *(float4*)&out[i] = v;
}

// ---------------- launch ----------------

extern "C" void kernel_launch(void* const* d_in, const int* in_sizes, int n_in,
                              void* d_out, int out_size, void* d_ws, size_t ws_size,
                              hipStream_t stream) {
    const int*   input_nodes = (const int*)d_in[0];
    const int*   esrc = (const int*)d_in[1];
    const int*   edst = (const int*)d_in[2];
    const float* emb  = (const float*)d_in[3];
    const float* Ws0  = (const float*)d_in[4];
    const float* Wn0  = (const float*)d_in[5];
    const float* b0   = (const float*)d_in[6];
    const float* Ws1  = (const float*)d_in[7];
    const float* Wn1  = (const float*)d_in[8];
    const float* b1   = (const float*)d_in[9];
    float* out = (float*)d_out;

    char* base = (char*)d_ws;
    float* hn      = (float*)(base);                    // 51,200,000 B
    float* h1      = (float*)(base + 51200000);         // 51,200,000 B
    int*   csr_src = (int*)  (base + 102400000);        //  6,400,000 B
    int*   row_ptr = (int*)  (base + 108800000);        //    200,004 B
    int*   deg     = (int*)  (base + 109000016);        //    200,000 B
    int*   cursor  = (int*)  (base + 109200016);        //    200,000 B
    int*   bsums   = (int*)  (base + 109400016);        //      1,024 B
    int*   boffs   = (int*)  (base + 109401040);        //      1,024 B
    float* nrm     = (float*)(base + 109402064);        //          4 B

    const int NB = (NN + 255) / 256;   // 196
    const int EB = (NE + 255) / 256;   // 6250

    k_zero  <<<NB, 256, 0, stream>>>(deg, cursor, nrm);
    k_hist  <<<EB, 256, 0, stream>>>(edst, deg);
    k_scan1 <<<NB, 256, 0, stream>>>(deg, row_ptr, bsums);
    k_scan2 <<<1,  256, 0, stream>>>(bsums, boffs, NB);
    k_addoff<<<NB, 256, 0, stream>>>(row_ptr, boffs);
    k_fill  <<<EB, 256, 0, stream>>>(esrc, edst, row_ptr, cursor, csr_src);

    dim3 gg((NN + BM - 1) / BM, 2);

    // layer 0
    k_agg<<<NN / 4, 256, 0, stream>>>(emb, input_nodes, row_ptr, csr_src, hn);
    k_gemm<1, 0><<<gg, 256, 0, stream>>>(emb, input_nodes, hn, Ws0, Wn0, b0, h1, nullptr);

    // layer 1
    k_agg<<<NN / 4, 256, 0, stream>>>(h1, nullptr, row_ptr, csr_src, hn);
    k_gemm<0, 1><<<gg, 256, 0, stream>>>(h1, nullptr, hn, Ws1, Wn1, b1, out, nrm);

    k_scale<<<(NN * DF / 4) / 256, 256, 0, stream>>>(out, nrm);
}

// Round 2
// 571.058 us; speedup vs baseline: 2.0458x; 2.0458x over previous
//
#include <hip/hip_runtime.h>
#include <math.h>

#define NN 50000
#define NE 1600000
#define DF 256

typedef unsigned short ushortT;
typedef __attribute__((ext_vector_type(8))) short short8;
typedef __attribute__((ext_vector_type(4))) float floatx4;

__device__ __forceinline__ unsigned bf16rne(float f) {
    unsigned u = __float_as_uint(f);
    return (u + 0x7fffu + ((u >> 16) & 1u)) >> 16;
}

#define ASYNC16(gptr, ldsptr) \
    __builtin_amdgcn_global_load_lds((const __attribute__((address_space(1))) unsigned*)(gptr), \
                                     (__attribute__((address_space(3))) unsigned*)(ldsptr), 16, 0, 0)

// ---------------- CSR build ----------------

__global__ void k_zero(int* __restrict__ deg, int* __restrict__ cursor, float* __restrict__ nrm) {
    int i = blockIdx.x * 256 + threadIdx.x;
    if (i < NN) { deg[i] = 0; cursor[i] = 0; }
    if (i == 0) *nrm = 0.0f;
}

__global__ void k_hist(const int* __restrict__ dst, int* __restrict__ deg) {
    int e = blockIdx.x * 256 + threadIdx.x;
    if (e < NE) atomicAdd(&deg[dst[e]], 1);
}

__global__ void k_scan1(const int* __restrict__ deg, int* __restrict__ row_ptr, int* __restrict__ bsums) {
    __shared__ int s[256];
    int t = threadIdx.x, i = blockIdx.x * 256 + t;
    int v = (i < NN) ? deg[i] : 0;
    s[t] = v; __syncthreads();
    for (int off = 1; off < 256; off <<= 1) {
        int x = (t >= off) ? s[t - off] : 0;
        __syncthreads();
        s[t] += x;
        __syncthreads();
    }
    if (i < NN) row_ptr[i] = s[t] - v;
    if (t == 255) bsums[blockIdx.x] = s[255];
}

__global__ void k_scan2(const int* __restrict__ bsums, int* __restrict__ boffs, int nb) {
    __shared__ int s[256];
    int t = threadIdx.x;
    int v = (t < nb) ? bsums[t] : 0;
    s[t] = v; __syncthreads();
    for (int off = 1; off < 256; off <<= 1) {
        int x = (t >= off) ? s[t - off] : 0;
        __syncthreads();
        s[t] += x;
        __syncthreads();
    }
    if (t < nb) boffs[t] = s[t] - v;
}

__global__ void k_addoff(int* __restrict__ row_ptr, const int* __restrict__ boffs) {
    int i = blockIdx.x * 256 + threadIdx.x;
    if (i < NN) row_ptr[i] += boffs[blockIdx.x];
    if (i == 0) row_ptr[NN] = NE;
}

__global__ void k_fill(const int* __restrict__ src, const int* __restrict__ dst,
                       const int* __restrict__ row_ptr, int* __restrict__ cursor,
                       int* __restrict__ csr_src) {
    int e = blockIdx.x * 256 + threadIdx.x;
    if (e < NE) {
        int d = dst[e];
        int pos = row_ptr[d] + atomicAdd(&cursor[d], 1);
        csr_src[pos] = src[e];
    }
}

// ---------------- conversions ----------------

// embb[i][c] = bf16(emb[gather[i]][c]); 8 elems/thread
__global__ __launch_bounds__(256)
void k_cvt_emb(const float* __restrict__ emb, const int* __restrict__ gather,
               ushortT* __restrict__ out) {
    long long i = ((long long)blockIdx.x * 256 + threadIdx.x) * 8;
    int row = (int)(i >> 8);
    int col = (int)(i & 255);
    long long g = (long long)gather[row] * 256 + col;
    float4 v0 = *(const float4*)(emb + g);
    float4 v1 = *(const float4*)(emb + g + 4);
    uint4 o;
    o.x = bf16rne(v0.x) | (bf16rne(v0.y) << 16);
    o.y = bf16rne(v0.z) | (bf16rne(v0.w) << 16);
    o.z = bf16rne(v1.x) | (bf16rne(v1.y) << 16);
    o.w = bf16rne(v1.z) | (bf16rne(v1.w) << 16);
    *(uint4*)(out + i) = o;
}

// Wt[n][k] (bf16, [256][512]) = k<256 ? Ws[k][n] : Wn[k-256][n]
__global__ __launch_bounds__(256)
void k_cvt_w(const float* __restrict__ Ws, const float* __restrict__ Wn,
             ushortT* __restrict__ Wt) {
    int idx = blockIdx.x * 256 + threadIdx.x;   // 131072 total
    int n = idx >> 9;
    int k = idx & 511;
    float v = (k < 256) ? Ws[k * 256 + n] : Wn[(k - 256) * 256 + n];
    Wt[idx] = (ushortT)bf16rne(v);
}

// ---------------- neighbor mean aggregation (bf16) ----------------
// one wave per node; halves of the wave take odd/even edges; 16B row-slices

__global__ __launch_bounds__(256)
void k_agg(const ushortT* __restrict__ feat, const int* __restrict__ row_ptr,
           const int* __restrict__ csr_src, ushortT* __restrict__ out) {
    int node = blockIdx.x * 4 + (threadIdx.x >> 6);
    int lane = threadIdx.x & 63;
    int half = lane >> 5;
    int l5 = lane & 31;
    if (node >= NN) return;
    int beg = row_ptr[node], end = row_ptr[node + 1];

    float s[8] = {0.f, 0.f, 0.f, 0.f, 0.f, 0.f, 0.f, 0.f};
    int p = beg + half;
    for (; p + 2 < end; p += 4) {
        long long r0 = (long long)csr_src[p] * 256 + l5 * 8;
        long long r1 = (long long)csr_src[p + 2] * 256 + l5 * 8;
        uint4 a = *(const uint4*)(feat + r0);
        uint4 b = *(const uint4*)(feat + r1);
        s[0] += __uint_as_float(a.x << 16) + __uint_as_float(b.x << 16);
        s[1] += __uint_as_float(a.x & 0xffff0000u) + __uint_as_float(b.x & 0xffff0000u);
        s[2] += __uint_as_float(a.y << 16) + __uint_as_float(b.y << 16);
        s[3] += __uint_as_float(a.y & 0xffff0000u) + __uint_as_float(b.y & 0xffff0000u);
        s[4] += __uint_as_float(a.z << 16) + __uint_as_float(b.z << 16);
        s[5] += __uint_as_float(a.z & 0xffff0000u) + __uint_as_float(b.z & 0xffff0000u);
        s[6] += __uint_as_float(a.w << 16) + __uint_as_float(b.w << 16);
        s[7] += __uint_as_float(a.w & 0xffff0000u) + __uint_as_float(b.w & 0xffff0000u);
    }
    for (; p < end; p += 2) {
        long long r0 = (long long)csr_src[p] * 256 + l5 * 8;
        uint4 a = *(const uint4*)(feat + r0);
        s[0] += __uint_as_float(a.x << 16);
        s[1] += __uint_as_float(a.x & 0xffff0000u);
        s[2] += __uint_as_float(a.y << 16);
        s[3] += __uint_as_float(a.y & 0xffff0000u);
        s[4] += __uint_as_float(a.z << 16);
        s[5] += __uint_as_float(a.z & 0xffff0000u);
        s[6] += __uint_as_float(a.w << 16);
        s[7] += __uint_as_float(a.w & 0xffff0000u);
    }
#pragma unroll
    for (int k = 0; k < 8; ++k) s[k] += __shfl_down(s[k], 32);

    if (half == 0) {
        float inv = 1.0f / fmaxf((float)(end - beg), 1.0f);
        uint4 o;
        o.x = bf16rne(s[0] * inv) | (bf16rne(s[1] * inv) << 16);
        o.y = bf16rne(s[2] * inv) | (bf16rne(s[3] * inv) << 16);
        o.z = bf16rne(s[4] * inv) | (bf16rne(s[5] * inv) << 16);
        o.w = bf16rne(s[6] * inv) | (bf16rne(s[7] * inv) << 16);
        *(uint4*)(out + (long long)node * 256 + l5 * 8) = o;
    }
}

// ---------------- fused dual GEMM, bf16 MFMA ----------------
// C[N,256] = [Aself|Aneigh](bf16) @ W(bf16,[512][256]) + bias
// Wt is pre-transposed [n=256][k=512]. 128x128 tile, BK=32, m97 structure.

template<int RELU, int NORM>
__global__ __launch_bounds__(256, 2)
void k_gemm(const ushortT* __restrict__ Aself, const ushortT* __restrict__ Aneigh,
            const ushortT* __restrict__ Wt, const float* __restrict__ bias,
            ushortT* __restrict__ Cb, float* __restrict__ Cf, float* __restrict__ norm_acc) {
    __shared__ ushortT As[4096];  // [128 m][32 k] bf16, 8 KB
    __shared__ ushortT Bs[4096];  // [128 n][32 k] bf16, 8 KB
    __shared__ float red[4];

    const int t = threadIdx.x;
    const int w = t >> 6;
    const int lane = t & 63;
    const int m0 = blockIdx.x * 128;
    const int n0 = blockIdx.y * 128;

    // staging: overall lane L = instr*256 + t; row = L>>2; 16B-chunk = L&3
    const int r0 = t >> 2;
    const int cu = (t & 3) * 8;   // ushort offset within 32-elem row

    const long long gA0 = (long long)min(m0 + r0, NN - 1) * 256;
    const long long gA1 = (long long)min(m0 + r0 + 64, NN - 1) * 256;
    const long long gB0 = (long long)(n0 + r0) * 512;
    const long long gB1 = (long long)(n0 + r0 + 64) * 512;

    // wave-uniform LDS bases (ushort units): instr0 -> w*512, instr1 -> 2048 + w*512
    const unsigned lds0 = w * 512;
    const unsigned lds1 = 2048 + w * 512;

    const int wm = w & 1, wn = w >> 1;
    const int fm = lane & 15;
    const int fk = (lane >> 4) * 8;

    floatx4 acc[4][4];
#pragma unroll
    for (int i = 0; i < 4; ++i)
#pragma unroll
        for (int j = 0; j < 4; ++j) acc[i][j] = (floatx4){0.f, 0.f, 0.f, 0.f};

    for (int kt = 0; kt < 512; kt += 32) {
        const ushortT* Ab; int kc;
        if (kt < 256) { Ab = Aself; kc = kt; } else { Ab = Aneigh; kc = kt - 256; }

        __syncthreads();
        ASYNC16(Ab + gA0 + kc + cu, As + lds0);
        ASYNC16(Ab + gA1 + kc + cu, As + lds1);
        ASYNC16(Wt + gB0 + kt + cu, Bs + lds0);
        ASYNC16(Wt + gB1 + kt + cu, Bs + lds1);
        __syncthreads();

        short8 af[4], bf[4];
#pragma unroll
        for (int i = 0; i < 4; ++i)
            af[i] = *(const short8*)&As[(wm * 64 + i * 16 + fm) * 32 + fk];
#pragma unroll
        for (int j = 0; j < 4; ++j)
            bf[j] = *(const short8*)&Bs[(wn * 64 + j * 16 + fm) * 32 + fk];
#pragma unroll
        for (int i = 0; i < 4; ++i)
#pragma unroll
            for (int j = 0; j < 4; ++j)
                acc[i][j] = __builtin_amdgcn_mfma_f32_16x16x32_bf16(af[i], bf[j], acc[i][j], 0, 0, 0);
    }

    // epilogue
    float bj[4];
#pragma unroll
    for (int j = 0; j < 4; ++j) bj[j] = bias[n0 + wn * 64 + j * 16 + fm];

    float sumsq = 0.0f;
#pragma unroll
    for (int i = 0; i < 4; ++i) {
#pragma unroll
        for (int r = 0; r < 4; ++r) {
            const int row = m0 + wm * 64 + i * 16 + (lane >> 4) * 4 + r;
            if (row < NN) {
#pragma unroll
                for (int j = 0; j < 4; ++j) {
                    const int col = n0 + wn * 64 + j * 16 + fm;
                    float v = acc[i][j][r] + bj[j];
                    if (RELU) v = fmaxf(v, 0.0f);
                    if (NORM) {
                        Cf[(long long)row * 256 + col] = v;
                        sumsq += v * v;
                    } else {
                        Cb[(long long)row * 256 + col] = (ushortT)bf16rne(v);
                    }
                }
            }
        }
    }

    if (NORM) {
#pragma unroll
        for (int off = 32; off > 0; off >>= 1) sumsq += __shfl_down(sumsq, off);
        if (lane == 0) red[w] = sumsq;
        __syncthreads();
        if (t == 0) atomicAdd(norm_acc, red[0] + red[1] + red[2] + red[3]);
    }
}

__global__ void k_scale(float* __restrict__ out, const float* __restrict__ nrm) {
    const float s = 1.0f / sqrtf(*nrm);
    long long i = ((long long)blockIdx.x * 256 + threadIdx.x) * 4;
    float4 v = *(float4*)&out[i];
    v.x *= s; v.y *= s; v.z *= s; v.w *= s;
    *(float4*)&out[i] = v;
}

// ---------------- launch ----------------

extern "C" void kernel_launch(void* const* d_in, const int* in_sizes, int n_in,
                              void* d_out, int out_size, void* d_ws, size_t ws_size,
                              hipStream_t stream) {
    const int*   input_nodes = (const int*)d_in[0];
    const int*   esrc = (const int*)d_in[1];
    const int*   edst = (const int*)d_in[2];
    const float* emb  = (const float*)d_in[3];
    const float* Ws0  = (const float*)d_in[4];
    const float* Wn0  = (const float*)d_in[5];
    const float* b0   = (const float*)d_in[6];
    const float* Ws1  = (const float*)d_in[7];
    const float* Wn1  = (const float*)d_in[8];
    const float* b1   = (const float*)d_in[9];
    float* out = (float*)d_out;

    char* base = (char*)d_ws;
    ushortT* embb   = (ushortT*)(base);                  // 25,600,000 B
    ushortT* h1b    = (ushortT*)(base + 25600000);       // 25,600,000 B
    ushortT* hnb    = (ushortT*)(base + 51200000);       // 25,600,000 B
    int*     csr_src= (int*)    (base + 76800000);       //  6,400,000 B
    ushortT* Wt0    = (ushortT*)(base + 83200000);       //    262,144 B
    ushortT* Wt1    = (ushortT*)(base + 83462144);       //    262,144 B
    int*     row_ptr= (int*)    (base + 83724288);       //    200,016 B
    int*     deg    = (int*)    (base + 83924304);       //    200,000 B
    int*     cursor = (int*)    (base + 84124304);       //    200,000 B
    int*     bsums  = (int*)    (base + 84324304);       //      1,024 B
    int*     boffs  = (int*)    (base + 84325328);       //      1,024 B
    float*   nrm    = (float*)  (base + 84326352);       //          4 B

    const int NB = (NN + 255) / 256;   // 196
    const int EB = (NE + 255) / 256;   // 6250

    k_zero   <<<NB, 256, 0, stream>>>(deg, cursor, nrm);
    k_hist   <<<EB, 256, 0, stream>>>(edst, deg);
    k_scan1  <<<NB, 256, 0, stream>>>(deg, row_ptr, bsums);
    k_scan2  <<<1,  256, 0, stream>>>(bsums, boffs, NB);
    k_addoff <<<NB, 256, 0, stream>>>(row_ptr, boffs);
    k_fill   <<<EB, 256, 0, stream>>>(esrc, edst, row_ptr, cursor, csr_src);

    k_cvt_emb<<<NN * DF / 8 / 256, 256, 0, stream>>>(emb, input_nodes, embb);
    k_cvt_w  <<<512, 256, 0, stream>>>(Ws0, Wn0, Wt0);
    k_cvt_w  <<<512, 256, 0, stream>>>(Ws1, Wn1, Wt1);

    dim3 gg((NN + 127) / 128, 2);   // (391, 2)

    // layer 0
    k_agg<<<NN / 4, 256, 0, stream>>>(embb, row_ptr, csr_src, hnb);
    k_gemm<1, 0><<<gg, 256, 0, stream>>>(embb, hnb, Wt0, b0, h1b, nullptr, nullptr);

    // layer 1
    k_agg<<<NN / 4, 256, 0, stream>>>(h1b, row_ptr, csr_src, hnb);
    k_gemm<0, 1><<<gg, 256, 0, stream>>>(h1b, hnb, Wt1, b1, nullptr, out, nrm);

    k_scale<<<NN * DF / 4 / 256, 256, 0, stream>>>(out, nrm);
}

// Round 3
// 471.609 us; speedup vs baseline: 2.4772x; 1.2109x over previous
//
#include <hip/hip_runtime.h>
#include <math.h>

#define NN 50000
#define NE 1600000
#define DF 256
#define NBUCK 391   // ceil(NN/128); bucket = dst >> 7

typedef unsigned short ushortT;
typedef __attribute__((ext_vector_type(8))) short short8;
typedef __attribute__((ext_vector_type(4))) float floatx4;

__device__ __forceinline__ unsigned bf16rne(float f) {
    unsigned u = __float_as_uint(f);
    return (u + 0x7fffu + ((u >> 16) & 1u)) >> 16;
}

#define ASYNC16(gptr, ldsptr) \
    __builtin_amdgcn_global_load_lds((const __attribute__((address_space(1))) unsigned*)(gptr), \
                                     (__attribute__((address_space(3))) unsigned*)(ldsptr), 16, 0, 0)

// ---------------- CSR build via bucket binning ----------------

__global__ void k_zero(int* __restrict__ bcnt) {
    int i = blockIdx.x * 256 + threadIdx.x;
    if (i < NBUCK) bcnt[i] = 0;
}

// per-block LDS histogram of bucket counts -> global
__global__ __launch_bounds__(256)
void k_bhist(const int* __restrict__ dst, int* __restrict__ bcnt) {
    __shared__ int h[NBUCK];
    for (int i = threadIdx.x; i < NBUCK; i += 256) h[i] = 0;
    __syncthreads();
    int base = blockIdx.x * 4096;
#pragma unroll
    for (int i = 0; i < 16; ++i) {
        int e = base + i * 256 + threadIdx.x;
        if (e < NE) atomicAdd(&h[dst[e] >> 7], 1);
    }
    __syncthreads();
    for (int i = threadIdx.x; i < NBUCK; i += 256)
        if (h[i]) atomicAdd(&bcnt[i], h[i]);
}

// scan bucket counts -> bases + cursors; also init nrm and row_ptr[NN]
__global__ void k_bscan(const int* __restrict__ bcnt, int* __restrict__ bbase,
                        int* __restrict__ cursor, int* __restrict__ row_ptr,
                        float* __restrict__ nrm) {
    __shared__ int s[512];
    int t = threadIdx.x;
    int v = (t < NBUCK) ? bcnt[t] : 0;
    s[t] = v; __syncthreads();
    for (int off = 1; off < 512; off <<= 1) {
        int x = (t >= off) ? s[t - off] : 0;
        __syncthreads();
        s[t] += x;
        __syncthreads();
    }
    if (t < NBUCK) { bbase[t] = s[t] - v; cursor[t] = s[t] - v; }
    if (t == 0) { bbase[NBUCK] = NE; row_ptr[NN] = NE; *nrm = 0.0f; }
}

// bin edges into bucket-grouped packed records: rec = src | (dst&127)<<16
__global__ __launch_bounds__(256)
void k_bin(const int* __restrict__ src, const int* __restrict__ dst,
           int* __restrict__ cursor, unsigned* __restrict__ rec) {
    __shared__ int h[NBUCK];
    __shared__ int gb[NBUCK];
    for (int i = threadIdx.x; i < NBUCK; i += 256) h[i] = 0;
    __syncthreads();
    const int base = blockIdx.x * 2048;
    int bk[8], rk[8];
    unsigned pk[8];
#pragma unroll
    for (int i = 0; i < 8; ++i) {
        int e = base + i * 256 + threadIdx.x;
        if (e < NE) {
            int d = dst[e];
            bk[i] = d >> 7;
            pk[i] = (unsigned)src[e] | ((unsigned)(d & 127) << 16);
            rk[i] = atomicAdd(&h[bk[i]], 1);
        } else bk[i] = -1;
    }
    __syncthreads();
    for (int i = threadIdx.x; i < NBUCK; i += 256) {
        int c = h[i];
        gb[i] = c ? atomicAdd(&cursor[i], c) : 0;
    }
    __syncthreads();
#pragma unroll
    for (int i = 0; i < 8; ++i)
        if (bk[i] >= 0) rec[gb[bk[i]] + rk[i]] = pk[i];
}

// one block per bucket: build row_ptr + dst-sorted csr (ushort src ids)
__global__ __launch_bounds__(256)
void k_csr(const unsigned* __restrict__ rec, const int* __restrict__ bbase,
           int* __restrict__ row_ptr, ushortT* __restrict__ csr) {
    __shared__ int cnt[128];
    __shared__ int cur[128];
    __shared__ int s[256];
    const int B = blockIdx.x, t = threadIdx.x;
    if (t < 128) cnt[t] = 0;
    __syncthreads();
    const int beg = bbase[B], end = bbase[B + 1];
    for (int p = beg + t; p < end; p += 256)
        atomicAdd(&cnt[(rec[p] >> 16) & 127], 1);
    __syncthreads();
    int v = (t < 128) ? cnt[t] : 0;
    s[t] = v; __syncthreads();
    for (int off = 1; off < 256; off <<= 1) {
        int x = (t >= off) ? s[t - off] : 0;
        __syncthreads();
        s[t] += x;
        __syncthreads();
    }
    if (t < 128) {
        int ex = s[t] - v;
        cur[t] = ex;
        int node = B * 128 + t;
        if (node < NN) row_ptr[node] = beg + ex;
    }
    __syncthreads();
    for (int p = beg + t; p < end; p += 256) {
        unsigned r = rec[p];
        int loc = atomicAdd(&cur[(r >> 16) & 127], 1);
        csr[beg + loc] = (ushortT)r;
    }
}

// ---------------- conversions ----------------

__global__ __launch_bounds__(256)
void k_cvt_emb(const float* __restrict__ emb, const int* __restrict__ gather,
               ushortT* __restrict__ out) {
    long long i = ((long long)blockIdx.x * 256 + threadIdx.x) * 8;
    int row = (int)(i >> 8);
    int col = (int)(i & 255);
    long long g = (long long)gather[row] * 256 + col;
    float4 v0 = *(const float4*)(emb + g);
    float4 v1 = *(const float4*)(emb + g + 4);
    uint4 o;
    o.x = bf16rne(v0.x) | (bf16rne(v0.y) << 16);
    o.y = bf16rne(v0.z) | (bf16rne(v0.w) << 16);
    o.z = bf16rne(v1.x) | (bf16rne(v1.y) << 16);
    o.w = bf16rne(v1.z) | (bf16rne(v1.w) << 16);
    *(uint4*)(out + i) = o;
}

__global__ __launch_bounds__(256)
void k_cvt_w(const float* __restrict__ Ws, const float* __restrict__ Wn,
             ushortT* __restrict__ Wt) {
    int idx = blockIdx.x * 256 + threadIdx.x;
    int n = idx >> 9;
    int k = idx & 511;
    float v = (k < 256) ? Ws[k * 256 + n] : Wn[(k - 256) * 256 + n];
    Wt[idx] = (ushortT)bf16rne(v);
}

// ---------------- neighbor mean aggregation (bf16, MLP=4) ----------------

__global__ __launch_bounds__(256)
void k_agg(const ushortT* __restrict__ feat, const int* __restrict__ row_ptr,
           const ushortT* __restrict__ csr, ushortT* __restrict__ out) {
    int node = blockIdx.x * 4 + (threadIdx.x >> 6);
    int lane = threadIdx.x & 63;
    int half = lane >> 5;
    int l5 = lane & 31;
    if (node >= NN) return;
    int beg = row_ptr[node], end = row_ptr[node + 1];

    float s[8] = {0.f, 0.f, 0.f, 0.f, 0.f, 0.f, 0.f, 0.f};
    int p = beg + half;

#define ACCUM(q) do { \
        s[0] += __uint_as_float(q.x << 16); \
        s[1] += __uint_as_float(q.x & 0xffff0000u); \
        s[2] += __uint_as_float(q.y << 16); \
        s[3] += __uint_as_float(q.y & 0xffff0000u); \
        s[4] += __uint_as_float(q.z << 16); \
        s[5] += __uint_as_float(q.z & 0xffff0000u); \
        s[6] += __uint_as_float(q.w << 16); \
        s[7] += __uint_as_float(q.w & 0xffff0000u); \
    } while (0)

    for (; p + 6 < end; p += 8) {
        long long r0 = (long long)csr[p]     * 256 + l5 * 8;
        long long r1 = (long long)csr[p + 2] * 256 + l5 * 8;
        long long r2 = (long long)csr[p + 4] * 256 + l5 * 8;
        long long r3 = (long long)csr[p + 6] * 256 + l5 * 8;
        uint4 a = *(const uint4*)(feat + r0);
        uint4 b = *(const uint4*)(feat + r1);
        uint4 c = *(const uint4*)(feat + r2);
        uint4 d = *(const uint4*)(feat + r3);
        ACCUM(a); ACCUM(b); ACCUM(c); ACCUM(d);
    }
    for (; p < end; p += 2) {
        long long r0 = (long long)csr[p] * 256 + l5 * 8;
        uint4 a = *(const uint4*)(feat + r0);
        ACCUM(a);
    }
#undef ACCUM

#pragma unroll
    for (int k = 0; k < 8; ++k) s[k] += __shfl_down(s[k], 32);

    if (half == 0) {
        float inv = 1.0f / fmaxf((float)(end - beg), 1.0f);
        uint4 o;
        o.x = bf16rne(s[0] * inv) | (bf16rne(s[1] * inv) << 16);
        o.y = bf16rne(s[2] * inv) | (bf16rne(s[3] * inv) << 16);
        o.z = bf16rne(s[4] * inv) | (bf16rne(s[5] * inv) << 16);
        o.w = bf16rne(s[6] * inv) | (bf16rne(s[7] * inv) << 16);
        *(uint4*)(out + (long long)node * 256 + l5 * 8) = o;
    }
}

// ---------------- fused dual GEMM, bf16 MFMA ----------------

template<int RELU, int NORM>
__global__ __launch_bounds__(256, 2)
void k_gemm(const ushortT* __restrict__ Aself, const ushortT* __restrict__ Aneigh,
            const ushortT* __restrict__ Wt, const float* __restrict__ bias,
            ushortT* __restrict__ Cb, float* __restrict__ Cf, float* __restrict__ norm_acc) {
    __shared__ ushortT As[4096];
    __shared__ ushortT Bs[4096];
    __shared__ float red[4];

    const int t = threadIdx.x;
    const int w = t >> 6;
    const int lane = t & 63;
    const int m0 = blockIdx.x * 128;
    const int n0 = blockIdx.y * 128;

    const int r0 = t >> 2;
    const int cu = (t & 3) * 8;

    const long long gA0 = (long long)min(m0 + r0, NN - 1) * 256;
    const long long gA1 = (long long)min(m0 + r0 + 64, NN - 1) * 256;
    const long long gB0 = (long long)(n0 + r0) * 512;
    const long long gB1 = (long long)(n0 + r0 + 64) * 512;

    const unsigned lds0 = w * 512;
    const unsigned lds1 = 2048 + w * 512;

    const int wm = w & 1, wn = w >> 1;
    const int fm = lane & 15;
    const int fk = (lane >> 4) * 8;

    floatx4 acc[4][4];
#pragma unroll
    for (int i = 0; i < 4; ++i)
#pragma unroll
        for (int j = 0; j < 4; ++j) acc[i][j] = (floatx4){0.f, 0.f, 0.f, 0.f};

    for (int kt = 0; kt < 512; kt += 32) {
        const ushortT* Ab; int kc;
        if (kt < 256) { Ab = Aself; kc = kt; } else { Ab = Aneigh; kc = kt - 256; }

        __syncthreads();
        ASYNC16(Ab + gA0 + kc + cu, As + lds0);
        ASYNC16(Ab + gA1 + kc + cu, As + lds1);
        ASYNC16(Wt + gB0 + kt + cu, Bs + lds0);
        ASYNC16(Wt + gB1 + kt + cu, Bs + lds1);
        __syncthreads();

        short8 af[4], bf[4];
#pragma unroll
        for (int i = 0; i < 4; ++i)
            af[i] = *(const short8*)&As[(wm * 64 + i * 16 + fm) * 32 + fk];
#pragma unroll
        for (int j = 0; j < 4; ++j)
            bf[j] = *(const short8*)&Bs[(wn * 64 + j * 16 + fm) * 32 + fk];
#pragma unroll
        for (int i = 0; i < 4; ++i)
#pragma unroll
            for (int j = 0; j < 4; ++j)
                acc[i][j] = __builtin_amdgcn_mfma_f32_16x16x32_bf16(af[i], bf[j], acc[i][j], 0, 0, 0);
    }

    float bj[4];
#pragma unroll
    for (int j = 0; j < 4; ++j) bj[j] = bias[n0 + wn * 64 + j * 16 + fm];

    float sumsq = 0.0f;
#pragma unroll
    for (int i = 0; i < 4; ++i) {
#pragma unroll
        for (int r = 0; r < 4; ++r) {
            const int row = m0 + wm * 64 + i * 16 + (lane >> 4) * 4 + r;
            if (row < NN) {
#pragma unroll
                for (int j = 0; j < 4; ++j) {
                    const int col = n0 + wn * 64 + j * 16 + fm;
                    float v = acc[i][j][r] + bj[j];
                    if (RELU) v = fmaxf(v, 0.0f);
                    if (NORM) {
                        Cf[(long long)row * 256 + col] = v;
                        sumsq += v * v;
                    } else {
                        Cb[(long long)row * 256 + col] = (ushortT)bf16rne(v);
                    }
                }
            }
        }
    }

    if (NORM) {
#pragma unroll
        for (int off = 32; off > 0; off >>= 1) sumsq += __shfl_down(sumsq, off);
        if (lane == 0) red[w] = sumsq;
        __syncthreads();
        if (t == 0) atomicAdd(norm_acc, red[0] + red[1] + red[2] + red[3]);
    }
}

__global__ void k_scale(float* __restrict__ out, const float* __restrict__ nrm) {
    const float s = 1.0f / sqrtf(*nrm);
    long long i = ((long long)blockIdx.x * 256 + threadIdx.x) * 4;
    float4 v = *(float4*)&out[i];
    v.x *= s; v.y *= s; v.z *= s; v.w *= s;
    *(float4*)&out[i] = v;
}

// ---------------- launch ----------------

extern "C" void kernel_launch(void* const* d_in, const int* in_sizes, int n_in,
                              void* d_out, int out_size, void* d_ws, size_t ws_size,
                              hipStream_t stream) {
    const int*   input_nodes = (const int*)d_in[0];
    const int*   esrc = (const int*)d_in[1];
    const int*   edst = (const int*)d_in[2];
    const float* emb  = (const float*)d_in[3];
    const float* Ws0  = (const float*)d_in[4];
    const float* Wn0  = (const float*)d_in[5];
    const float* b0   = (const float*)d_in[6];
    const float* Ws1  = (const float*)d_in[7];
    const float* Wn1  = (const float*)d_in[8];
    const float* b1   = (const float*)d_in[9];
    float* out = (float*)d_out;

    char* base = (char*)d_ws;
    ushortT*  embb    = (ushortT*) (base);                  // 25,600,000
    ushortT*  h1b     = (ushortT*) (base + 25600000);       // 25,600,000
    ushortT*  hnb     = (ushortT*) (base + 51200000);       // 25,600,000
    unsigned* rec     = (unsigned*)(base + 76800000);       //  6,400,000
    ushortT*  csr     = (ushortT*) (base + 83200000);       //  3,200,000
    ushortT*  Wt0     = (ushortT*) (base + 86400000);       //    262,144
    ushortT*  Wt1     = (ushortT*) (base + 86662144);       //    262,144
    int*      row_ptr = (int*)     (base + 86924288);       //    200,016
    int*      bcnt    = (int*)     (base + 87124304);       //      1,600
    int*      bbase   = (int*)     (base + 87125904);       //      1,600
    int*      cursor  = (int*)     (base + 87127504);       //      1,600
    float*    nrm     = (float*)   (base + 87129104);       //          4

    k_zero  <<<2,   256, 0, stream>>>(bcnt);
    k_bhist <<<391, 256, 0, stream>>>(edst, bcnt);
    k_bscan <<<1,   512, 0, stream>>>(bcnt, bbase, cursor, row_ptr, nrm);
    k_bin   <<<782, 256, 0, stream>>>(esrc, edst, cursor, rec);
    k_csr   <<<NBUCK, 256, 0, stream>>>(rec, bbase, row_ptr, csr);

    k_cvt_emb<<<NN * DF / 8 / 256, 256, 0, stream>>>(emb, input_nodes, embb);
    k_cvt_w  <<<512, 256, 0, stream>>>(Ws0, Wn0, Wt0);
    k_cvt_w  <<<512, 256, 0, stream>>>(Ws1, Wn1, Wt1);

    dim3 gg((NN + 127) / 128, 2);

    // layer 0
    k_agg<<<NN / 4, 256, 0, stream>>>(embb, row_ptr, csr, hnb);
    k_gemm<1, 0><<<gg, 256, 0, stream>>>(embb, hnb, Wt0, b0, h1b, nullptr, nullptr);

    // layer 1
    k_agg<<<NN / 4, 256, 0, stream>>>(h1b, row_ptr, csr, hnb);
    k_gemm<0, 1><<<gg, 256, 0, stream>>>(h1b, hnb, Wt1, b1, nullptr, out, nrm);

    k_scale<<<NN * DF / 4 / 256, 256, 0, stream>>>(out, nrm);
}